// Round 3
// baseline (5091.475 us; speedup 1.0000x reference)
//
#include <hip/hip_runtime.h>
#include <hip/hip_fp16.h>
#include <stdint.h>
#include <type_traits>

// ClockworkRNN MI355X round 3.
// (1) cvt X->f16, W->W^T f16; (2) per-module compact x-projection GEMM (f16
// MFMA 16x16x32) -- unchanged from R1 (verified passing); (3) scan rewritten:
// 1 WG (512 thr, 8 waves) per batch, double-buffered h + ONE barrier/step,
// fast tanh, register weights m0/m1/m2 (K-split + shfl), NO-SPLIT m3..m7
// (one wave owns a module's 64 cols, col = lane, full dot per lane; h reads
// broadcast, LDS weight reads lane-consecutive). No arrays for per-lane state.
// ws layout (bytes): [0, 67108864) X f16 | [67108864, 67371008) W^T f16 |
//                    [67371008, 100794368) compact x f16.

typedef _Float16 half_t;
typedef _Float16 h2 __attribute__((ext_vector_type(2)));
typedef _Float16 h8 __attribute__((ext_vector_type(8)));
typedef float f4 __attribute__((ext_vector_type(4)));

__device__ __forceinline__ float dot2f(h2 a, h2 b, float c) {
#if defined(__has_builtin)
#if __has_builtin(__builtin_amdgcn_fdot2)
  return __builtin_amdgcn_fdot2(a, b, c, false);
#else
  return c + (float)a[0] * (float)b[0] + (float)a[1] * (float)b[1];
#endif
#else
  return c + (float)a[0] * (float)b[0] + (float)a[1] * (float)b[1];
#endif
}

__device__ __forceinline__ float fast_tanh(float x) {
  // tanh(x) = 1 - 2/(exp2(2*log2e*x)+1)
#if defined(__has_builtin)
#if __has_builtin(__builtin_amdgcn_exp2f) && __has_builtin(__builtin_amdgcn_rcpf)
  float e = __builtin_amdgcn_exp2f(x * 2.885390081777927f);
  return 1.0f - 2.0f * __builtin_amdgcn_rcpf(e + 1.0f);
#else
  float e = __builtin_exp2f(x * 2.885390081777927f);
  return 1.0f - 2.0f / (e + 1.0f);
#endif
#else
  float e = exp2f(x * 2.885390081777927f);
  return 1.0f - 2.0f / (e + 1.0f);
#endif
}

__device__ __forceinline__ void gl_lds16(const half_t* g, half_t* l) {
  __builtin_amdgcn_global_load_lds(
      (__attribute__((address_space(1))) void*)(void*)g,
      (__attribute__((address_space(3))) void*)(void*)l, 16, 0, 0);
}

// ---------------- cvt kernels (unchanged, verified) ----------------
__global__ void cw_cvt_x(const float* __restrict__ X, half_t* __restrict__ Xh, long n4) {
  long i = (long)blockIdx.x * blockDim.x + threadIdx.x;
  const long stride = (long)gridDim.x * blockDim.x;
  const float4* X4 = (const float4*)X;
  h2* out2 = (h2*)Xh;
  for (; i < n4; i += stride) {
    float4 v = X4[i];
    h2 a; a[0] = (half_t)v.x; a[1] = (half_t)v.y;
    h2 b; b[0] = (half_t)v.z; b[1] = (half_t)v.w;
    out2[2 * i] = a;
    out2[2 * i + 1] = b;
  }
}

__global__ void cw_cvt_wt(const float* __restrict__ W, half_t* __restrict__ WT) {
  int idx = blockIdx.x * 256 + threadIdx.x;  // 131072 total
  int o = idx >> 8, d = idx & 255;
  WT[idx] = (half_t)W[d * 512 + o];
}

// ---------------- x projection (unchanged, verified) ----------------
__global__ __launch_bounds__(256) void cw_xproj(const half_t* __restrict__ Xh,
                                                const half_t* __restrict__ WT,
                                                const float* __restrict__ bias,
                                                half_t* __restrict__ xout) {
  const int mod = blockIdx.y;
  const int Ti = 2048 >> mod;
  const long Mi = (long)64 * Ti;
  const long m0r = (long)blockIdx.x * 256;
  if (m0r >= Mi) return;
  __shared__ alignas(16) half_t Bs[64 * 256];
  __shared__ alignas(16) half_t As[256 * 64];
  const int tid = threadIdx.x;
  const int wv = tid >> 6, l = tid & 63;
  const int lr = l & 15, lk = (l >> 4) * 8;
  const int shf = 11 - mod;

#pragma unroll
  for (int it = 0; it < 8; ++it) {
    int slot = it * 256 + tid;
    int n = slot >> 5, kc = slot & 31;
    gl_lds16(WT + ((mod << 6) + n) * 256 + kc * 8, Bs + slot * 8);
  }

  f4 acc[4][4];
#pragma unroll
  for (int a = 0; a < 4; ++a)
#pragma unroll
    for (int bq = 0; bq < 4; ++bq) acc[a][bq] = f4{0.f, 0.f, 0.f, 0.f};

  for (int kt = 0; kt < 4; ++kt) {
#pragma unroll
    for (int it = 0; it < 8; ++it) {
      int slot = it * 256 + tid;
      int r = slot >> 3, kc = slot & 7;
      long m = m0r + r;
      long g = (m >> shf) * 2048 + ((m & (long)(Ti - 1)) << mod);
      gl_lds16(Xh + g * 256 + kt * 64 + kc * 8, As + slot * 8);
    }
    __syncthreads();
#pragma unroll
    for (int ks = 0; ks < 2; ++ks) {
      h8 af[4], bf[4];
#pragma unroll
      for (int mi = 0; mi < 4; ++mi)
        af[mi] = *(const h8*)&As[(wv * 64 + mi * 16 + lr) * 64 + ks * 32 + lk];
#pragma unroll
      for (int ni = 0; ni < 4; ++ni)
        bf[ni] = *(const h8*)&Bs[(ni * 16 + lr) * 256 + kt * 64 + ks * 32 + lk];
#pragma unroll
      for (int mi = 0; mi < 4; ++mi)
#pragma unroll
        for (int ni = 0; ni < 4; ++ni)
          acc[mi][ni] = __builtin_amdgcn_mfma_f32_16x16x32_f16(af[mi], bf[ni], acc[mi][ni], 0, 0, 0);
    }
    __syncthreads();
  }

  const long xb = 16777216L - (16777216L >> mod);
#pragma unroll
  for (int ni = 0; ni < 4; ++ni) {
    int n = ni * 16 + lr;
    float bv = bias[(mod << 6) + n];
#pragma unroll
    for (int mi = 0; mi < 4; ++mi) {
      f4 cf = acc[mi][ni];
#pragma unroll
      for (int q = 0; q < 4; ++q) {
        long m = m0r + wv * 64 + mi * 16 + (l >> 4) * 4 + q;
        xout[xb + m * 64 + n] = (half_t)(cf[q] + bv);
      }
    }
  }
}

// ---------------- scan round 3 ----------------
// Roles (8 waves):
//   waves 0-3: m0. chunk q0=l>>4 (4 x 128 rows), col c0 = wv*16+(l&15).
//   waves 4-5: m1. chunk q1=l>>5 (2 x 224 rows), col cc = (wv&1)*32+(l&31).
//   waves 6-7: m2 K-split (chunk q1, col cc) PLUS no-split modules:
//     wave 6: m4 (col=l, 128 pairs, per 16), m6 (col=l, 64 pairs, per 64)
//     wave 7: m3 (col=l, 160 pairs, per 8), m5 (96 pairs, per 32), m7 (32 pairs, per 128)
// m3..m7 f16 weights in LDS at [base + p*64 + col] (lane-consecutive reads).

template <int PAIRS>
__device__ __forceinline__ float dotL(const h2* hp, const h2* wp) {
  float a0 = 0.f, a1 = 0.f, a2 = 0.f, a3 = 0.f;
#pragma unroll
  for (int p = 0; p < PAIRS; p += 4) {
    a0 = dot2f(hp[p], wp[(p) * 64], a0);
    a1 = dot2f(hp[p + 1], wp[(p + 1) * 64], a1);
    a2 = dot2f(hp[p + 2], wp[(p + 2) * 64], a2);
    a3 = dot2f(hp[p + 3], wp[(p + 3) * 64], a3);
  }
  return (a0 + a1) + (a2 + a3);
}

__global__ __launch_bounds__(512, 1) void cw_scan3(
    const half_t* __restrict__ xbuf,
    const float* __restrict__ Wc0, const float* __restrict__ Wc1,
    const float* __restrict__ Wc2, const float* __restrict__ Wc3,
    const float* __restrict__ Wc4, const float* __restrict__ Wc5,
    const float* __restrict__ Wc6, const float* __restrict__ Wc7,
    float* __restrict__ out) {
  const int b = blockIdx.x;
  const int tid = threadIdx.x;
  const int wv = tid >> 6;
  const int l = tid & 63;

  __shared__ alignas(16) half_t hbuf[2][512];
  __shared__ h2 wlds[30720];  // m3:0(160p) m4:10240(128p) m5:18432(96p) m6:24576(64p) m7:28672(32p)

  const int q0 = l >> 4;
  const int c0 = (wv << 4) + (l & 15);
  const int q1 = l >> 5;
  const int cc = ((wv & 1) << 5) + (l & 31);  // m1 col (wv4,5) / m2 col (wv6,7)

  h2 wreg[112];
#pragma unroll
  for (int p = 0; p < 112; ++p) wreg[p] = h2{(half_t)0.f, (half_t)0.f};

  float hs0 = 0.f, hsA = 0.f, hsB = 0.f, hsC = 0.f;
  float xr0 = 0.f, xr1 = 0.f, xr2 = 0.f, xr3 = 0.f;
  float xrA = 0.f, xrB = 0.f, xrC = 0.f;

  // ---- register weights ----
  if (wv < 4) {
#pragma unroll
    for (int p = 0; p < 64; ++p) {
      int r = (q0 << 7) + 2 * p;
      wreg[p] = h2{(half_t)Wc0[r * 64 + c0], (half_t)Wc0[(r + 1) * 64 + c0]};
    }
  } else if (wv < 6) {
#pragma unroll
    for (int p = 0; p < 112; ++p) {
      int r = q1 * 224 + 2 * p;
      wreg[p] = h2{(half_t)Wc1[r * 64 + cc], (half_t)Wc1[(r + 1) * 64 + cc]};
    }
  } else {
#pragma unroll
    for (int p = 0; p < 96; ++p) {
      int r = q1 * 192 + 2 * p;
      wreg[p] = h2{(half_t)Wc2[r * 64 + cc], (half_t)Wc2[(r + 1) * 64 + cc]};
    }
  }

  // ---- m3..m7 weights -> LDS (simple [p][col] layout) ----
  for (int e = tid; e < 160 * 64; e += 512) {
    int p = e >> 6, col = e & 63;
    wlds[0 + e] = h2{(half_t)Wc3[(2 * p) * 64 + col], (half_t)Wc3[(2 * p + 1) * 64 + col]};
  }
  for (int e = tid; e < 128 * 64; e += 512) {
    int p = e >> 6, col = e & 63;
    wlds[10240 + e] = h2{(half_t)Wc4[(2 * p) * 64 + col], (half_t)Wc4[(2 * p + 1) * 64 + col]};
  }
  for (int e = tid; e < 96 * 64; e += 512) {
    int p = e >> 6, col = e & 63;
    wlds[18432 + e] = h2{(half_t)Wc5[(2 * p) * 64 + col], (half_t)Wc5[(2 * p + 1) * 64 + col]};
  }
  for (int e = tid; e < 64 * 64; e += 512) {
    int p = e >> 6, col = e & 63;
    wlds[24576 + e] = h2{(half_t)Wc6[(2 * p) * 64 + col], (half_t)Wc6[(2 * p + 1) * 64 + col]};
  }
  for (int e = tid; e < 32 * 64; e += 512) {
    int p = e >> 6, col = e & 63;
    wlds[28672 + e] = h2{(half_t)Wc7[(2 * p) * 64 + col], (half_t)Wc7[(2 * p + 1) * 64 + col]};
  }
  hbuf[0][tid] = (half_t)0.f;
  hbuf[1][tid] = (half_t)0.f;

  // ---- x pointers (compact layout; bases in halves) ----
  const half_t* xp0 = xbuf + ((long)b << 17) + c0;             // m0: b*2048*64
  const half_t* xp1 = xbuf + 8388608L + ((long)b << 16) + cc;  // m1: b*1024*64
  const half_t* xp2 = xbuf + 12582912L + ((long)b << 15) + cc; // m2: b*512*64
  const half_t* xpA = xbuf;
  const half_t* xpB = xbuf;
  const half_t* xpC = xbuf;
  if (wv == 6) {
    xpA = xbuf + 15728640L + ((long)b << 13) + l;  // m4: b*128*64
    xpB = xbuf + 16515072L + ((long)b << 11) + l;  // m6: b*32*64
  } else if (wv == 7) {
    xpA = xbuf + 14680064L + ((long)b << 14) + l;  // m3: b*256*64
    xpB = xbuf + 16252928L + ((long)b << 12) + l;  // m5: b*64*64
    xpC = xbuf + 16646144L + ((long)b << 10) + l;  // m7: b*16*64
  }

  // ---- initial prefetch ----
  if (wv < 4) {
    if (l < 16) {
      xr0 = (float)xp0[0];
      xr1 = (float)xp0[64];
      xr2 = (float)xp0[128];
      xr3 = (float)xp0[192];
    }
  } else if (wv < 6) {
    if (l < 32) {
      xr0 = (float)xp1[0];
      xr1 = (float)xp1[64];
    }
  } else if (wv == 6) {
    if (l < 32) xr0 = (float)xp2[0];
    xrA = (float)xpA[0];
    xrB = (float)xpB[0];
  } else {
    if (l < 32) xr0 = (float)xp2[0];
    xrA = (float)xpA[0];
    xrB = (float)xpB[0];
    xrC = (float)xpC[0];
  }
  __syncthreads();

  auto step = [&](auto offc, int t, const half_t* hin, half_t* hout) {
    constexpr int OFF = decltype(offc)::value;
    const h2* hin2 = (const h2*)hin;
    if (wv < 4) {
      // ---- m0: every step ----
      const h2* hp = hin2 + (q0 << 6);
      float a0 = 0.f, a1 = 0.f, a2 = 0.f, a3 = 0.f;
#pragma unroll
      for (int g = 0; g < 16; ++g) {
        int gg = (g + 2 * q0) & 15;  // bank-stagger across the 4 chunks
        a0 = dot2f(hp[gg * 4 + 0], wreg[gg * 4 + 0], a0);
        a1 = dot2f(hp[gg * 4 + 1], wreg[gg * 4 + 1], a1);
        a2 = dot2f(hp[gg * 4 + 2], wreg[gg * 4 + 2], a2);
        a3 = dot2f(hp[gg * 4 + 3], wreg[gg * 4 + 3], a3);
      }
      float v = (a0 + a1) + (a2 + a3);
      v += __shfl_xor(v, 16);
      v += __shfl_xor(v, 32);
      if (l < 16) {
        float xv;
        if constexpr (OFF == 0) xv = xr0;
        else if constexpr (OFF == 1) xv = xr1;
        else if constexpr (OFF == 2) xv = xr2;
        else xv = xr3;
        hs0 = fast_tanh(v + xv);
        hout[c0] = (half_t)hs0;
        int tn = t + OFF + 4;
        if (tn < 2048) {
          float nv = (float)xp0[(long)tn << 6];
          if constexpr (OFF == 0) xr0 = nv;
          else if constexpr (OFF == 1) xr1 = nv;
          else if constexpr (OFF == 2) xr2 = nv;
          else xr3 = nv;
        }
      }
    } else if (wv < 6) {
      // ---- m1: update on even t ----
      if constexpr ((OFF & 1) == 0) {
        const h2* hp = hin2 + 32 + 112 * q1;
        float a0 = 0.f, a1 = 0.f, a2 = 0.f, a3 = 0.f;
#pragma unroll
        for (int p = 0; p < 112; p += 4) {
          a0 = dot2f(hp[p], wreg[p], a0);
          a1 = dot2f(hp[p + 1], wreg[p + 1], a1);
          a2 = dot2f(hp[p + 2], wreg[p + 2], a2);
          a3 = dot2f(hp[p + 3], wreg[p + 3], a3);
        }
        float v = (a0 + a1) + (a2 + a3);
        v += __shfl_xor(v, 32);
        if (l < 32) {
          float xv = (OFF == 0) ? xr0 : xr1;
          hs0 = fast_tanh(v + xv);
          hout[64 + cc] = (half_t)hs0;
          int tn = t + OFF + 4;
          if (tn < 2048) {
            float nv = (float)xp1[(long)(tn >> 1) << 6];
            if constexpr (OFF == 0) xr0 = nv;
            else xr1 = nv;
          }
        }
      } else {
        if (l < 32) {
          hs0 = fast_tanh(hs0);
          hout[64 + cc] = (half_t)hs0;
        }
      }
    } else if (wv == 6) {
      // ---- m2-half + m4 + m6 ----
      float v2 = 0.f, dA = 0.f, dB = 0.f;
      bool uA = false, uB = false;
      if constexpr (OFF == 0) {
        const h2* hp = hin2 + 64 + 96 * q1;
        float a0 = 0.f, a1 = 0.f, a2 = 0.f, a3 = 0.f;
#pragma unroll
        for (int p = 0; p < 96; p += 4) {
          a0 = dot2f(hp[p], wreg[p], a0);
          a1 = dot2f(hp[p + 1], wreg[p + 1], a1);
          a2 = dot2f(hp[p + 2], wreg[p + 2], a2);
          a3 = dot2f(hp[p + 3], wreg[p + 3], a3);
        }
        v2 = (a0 + a1) + (a2 + a3);
        v2 += __shfl_xor(v2, 32);
        uA = (t & 15) == 0;
        uB = (t & 63) == 0;
        if (uA) dA = dotL<128>(hin2 + 128, wlds + 10240 + l);
        if (uB) dB = dotL<64>(hin2 + 192, wlds + 24576 + l);
      }
      if (l < 32) {
        if constexpr (OFF == 0) {
          hs0 = fast_tanh(v2 + xr0);
          int ni = (t >> 2) + 1;
          if (ni < 512) xr0 = (float)xp2[(long)ni << 6];
        } else {
          hs0 = fast_tanh(hs0);
        }
        hout[128 + cc] = (half_t)hs0;
      }
      if (OFF == 0 && uA) {
        hsA = fast_tanh(dA + xrA);
        int ni = (t >> 4) + 1;
        if (ni < 128) xrA = (float)xpA[(long)ni << 6];
      } else {
        hsA = fast_tanh(hsA);
      }
      hout[256 + l] = (half_t)hsA;
      if (OFF == 0 && uB) {
        hsB = fast_tanh(dB + xrB);
        int ni = (t >> 6) + 1;
        if (ni < 32) xrB = (float)xpB[(long)ni << 6];
      } else {
        hsB = fast_tanh(hsB);
      }
      hout[384 + l] = (half_t)hsB;
    } else {
      // ---- m2-half + m3 + m5 + m7 ----
      float v2 = 0.f, dA = 0.f, dB = 0.f, dC = 0.f;
      bool uA = false, uB = false, uC = false;
      if constexpr (OFF == 0) {
        const h2* hp = hin2 + 64 + 96 * q1;
        float a0 = 0.f, a1 = 0.f, a2 = 0.f, a3 = 0.f;
#pragma unroll
        for (int p = 0; p < 96; p += 4) {
          a0 = dot2f(hp[p], wreg[p], a0);
          a1 = dot2f(hp[p + 1], wreg[p + 1], a1);
          a2 = dot2f(hp[p + 2], wreg[p + 2], a2);
          a3 = dot2f(hp[p + 3], wreg[p + 3], a3);
        }
        v2 = (a0 + a1) + (a2 + a3);
        v2 += __shfl_xor(v2, 32);
        uA = (t & 7) == 0;
        uB = (t & 31) == 0;
        uC = (t & 127) == 0;
        if (uA) dA = dotL<160>(hin2 + 96, wlds + 0 + l);
        if (uB) dB = dotL<96>(hin2 + 160, wlds + 18432 + l);
        if (uC) dC = dotL<32>(hin2 + 224, wlds + 28672 + l);
      }
      if (l < 32) {
        if constexpr (OFF == 0) {
          hs0 = fast_tanh(v2 + xr0);
          int ni = (t >> 2) + 1;
          if (ni < 512) xr0 = (float)xp2[(long)ni << 6];
        } else {
          hs0 = fast_tanh(hs0);
        }
        hout[128 + cc] = (half_t)hs0;
      }
      if (OFF == 0 && uA) {
        hsA = fast_tanh(dA + xrA);
        int ni = (t >> 3) + 1;
        if (ni < 256) xrA = (float)xpA[(long)ni << 6];
      } else {
        hsA = fast_tanh(hsA);
      }
      hout[192 + l] = (half_t)hsA;
      if (OFF == 0 && uB) {
        hsB = fast_tanh(dB + xrB);
        int ni = (t >> 5) + 1;
        if (ni < 64) xrB = (float)xpB[(long)ni << 6];
      } else {
        hsB = fast_tanh(hsB);
      }
      hout[320 + l] = (half_t)hsB;
      if (OFF == 0 && uC) {
        hsC = fast_tanh(dC + xrC);
        int ni = (t >> 7) + 1;
        if (ni < 16) xrC = (float)xpC[(long)ni << 6];
      } else {
        hsC = fast_tanh(hsC);
      }
      hout[448 + l] = (half_t)hsC;
    }
    __syncthreads();
  };

  for (int t = 0; t < 2048; t += 4) {
    step(std::integral_constant<int, 0>{}, t, hbuf[0], hbuf[1]);
    step(std::integral_constant<int, 1>{}, t, hbuf[1], hbuf[0]);
    step(std::integral_constant<int, 2>{}, t, hbuf[0], hbuf[1]);
    step(std::integral_constant<int, 3>{}, t, hbuf[1], hbuf[0]);
  }

  // ---- output ----
  float* ob = out + ((long)b << 9);
  if (wv < 4) {
    if (l < 16) ob[c0] = hs0;
  } else if (wv < 6) {
    if (l < 32) ob[64 + cc] = hs0;
  } else if (wv == 6) {
    if (l < 32) ob[128 + cc] = hs0;
    ob[256 + l] = hsA;
    ob[384 + l] = hsB;
  } else {
    if (l < 32) ob[128 + cc] = hs0;
    ob[192 + l] = hsA;
    ob[320 + l] = hsB;
    ob[448 + l] = hsC;
  }
}

// ---------------- launcher ----------------
extern "C" void kernel_launch(void* const* d_in, const int* in_sizes, int n_in,
                              void* d_out, int out_size, void* d_ws, size_t ws_size,
                              hipStream_t stream) {
  const float* X = (const float*)d_in[0];
  const float* W = (const float*)d_in[1];
  const float* bias = (const float*)d_in[2];
  const float* Wc0 = (const float*)d_in[3];
  const float* Wc1 = (const float*)d_in[4];
  const float* Wc2 = (const float*)d_in[5];
  const float* Wc3 = (const float*)d_in[6];
  const float* Wc4 = (const float*)d_in[7];
  const float* Wc5 = (const float*)d_in[8];
  const float* Wc6 = (const float*)d_in[9];
  const float* Wc7 = (const float*)d_in[10];
  float* out = (float*)d_out;

  half_t* Xh = (half_t*)d_ws;                       // 67,108,864 B
  half_t* WT = (half_t*)((char*)d_ws + 67108864);   //    262,144 B
  half_t* xbuf = (half_t*)((char*)d_ws + 67371008); // 33,423,360 B

  cw_cvt_x<<<4096, 256, 0, stream>>>(X, Xh, 8388608L);
  cw_cvt_wt<<<512, 256, 0, stream>>>(W, WT);
  dim3 g(512, 8);
  cw_xproj<<<g, 256, 0, stream>>>(Xh, WT, bias, xbuf);
  cw_scan3<<<64, 512, 0, stream>>>(xbuf, Wc0, Wc1, Wc2, Wc3, Wc4, Wc5, Wc6, Wc7, out);
}

// Round 4
// 2157.971 us; speedup vs baseline: 2.3594x; 2.3594x over previous
//
#include <hip/hip_runtime.h>
#include <hip/hip_fp16.h>
#include <stdint.h>
#include <type_traits>

// ClockworkRNN MI355X round 4.
// R3 structure (verified correct) with the scratch-spill bug fixed:
// m0's bank-rotation is now applied to the WEIGHT LOAD (static wreg index,
// rotated row at init) and only the LDS h-address is runtime-rotated.
// Rule #20: runtime-indexed register arrays go to scratch -- R3's
// wreg[(g+2*q0)&15 ...] caused a 15MB spill (WRITE_SIZE) and 2x slowdown.
// ws layout (bytes): [0, 67108864) X f16 | [67108864, 67371008) W^T f16 |
//                    [67371008, 100794368) compact x f16.

typedef _Float16 half_t;
typedef _Float16 h2 __attribute__((ext_vector_type(2)));
typedef _Float16 h8 __attribute__((ext_vector_type(8)));
typedef float f4 __attribute__((ext_vector_type(4)));

__device__ __forceinline__ float dot2f(h2 a, h2 b, float c) {
#if defined(__has_builtin)
#if __has_builtin(__builtin_amdgcn_fdot2)
  return __builtin_amdgcn_fdot2(a, b, c, false);
#else
  return c + (float)a[0] * (float)b[0] + (float)a[1] * (float)b[1];
#endif
#else
  return c + (float)a[0] * (float)b[0] + (float)a[1] * (float)b[1];
#endif
}

__device__ __forceinline__ float fast_tanh(float x) {
  // tanh(x) = 1 - 2/(exp2(2*log2e*x)+1)
#if defined(__has_builtin)
#if __has_builtin(__builtin_amdgcn_exp2f) && __has_builtin(__builtin_amdgcn_rcpf)
  float e = __builtin_amdgcn_exp2f(x * 2.885390081777927f);
  return 1.0f - 2.0f * __builtin_amdgcn_rcpf(e + 1.0f);
#else
  float e = __builtin_exp2f(x * 2.885390081777927f);
  return 1.0f - 2.0f / (e + 1.0f);
#endif
#else
  float e = exp2f(x * 2.885390081777927f);
  return 1.0f - 2.0f / (e + 1.0f);
#endif
}

__device__ __forceinline__ void gl_lds16(const half_t* g, half_t* l) {
  __builtin_amdgcn_global_load_lds(
      (__attribute__((address_space(1))) void*)(void*)g,
      (__attribute__((address_space(3))) void*)(void*)l, 16, 0, 0);
}

// ---------------- cvt kernels (unchanged, verified) ----------------
__global__ void cw_cvt_x(const float* __restrict__ X, half_t* __restrict__ Xh, long n4) {
  long i = (long)blockIdx.x * blockDim.x + threadIdx.x;
  const long stride = (long)gridDim.x * blockDim.x;
  const float4* X4 = (const float4*)X;
  h2* out2 = (h2*)Xh;
  for (; i < n4; i += stride) {
    float4 v = X4[i];
    h2 a; a[0] = (half_t)v.x; a[1] = (half_t)v.y;
    h2 b; b[0] = (half_t)v.z; b[1] = (half_t)v.w;
    out2[2 * i] = a;
    out2[2 * i + 1] = b;
  }
}

__global__ void cw_cvt_wt(const float* __restrict__ W, half_t* __restrict__ WT) {
  int idx = blockIdx.x * 256 + threadIdx.x;  // 131072 total
  int o = idx >> 8, d = idx & 255;
  WT[idx] = (half_t)W[d * 512 + o];
}

// ---------------- x projection (unchanged, verified) ----------------
__global__ __launch_bounds__(256) void cw_xproj(const half_t* __restrict__ Xh,
                                                const half_t* __restrict__ WT,
                                                const float* __restrict__ bias,
                                                half_t* __restrict__ xout) {
  const int mod = blockIdx.y;
  const int Ti = 2048 >> mod;
  const long Mi = (long)64 * Ti;
  const long m0r = (long)blockIdx.x * 256;
  if (m0r >= Mi) return;
  __shared__ alignas(16) half_t Bs[64 * 256];
  __shared__ alignas(16) half_t As[256 * 64];
  const int tid = threadIdx.x;
  const int wv = tid >> 6, l = tid & 63;
  const int lr = l & 15, lk = (l >> 4) * 8;
  const int shf = 11 - mod;

#pragma unroll
  for (int it = 0; it < 8; ++it) {
    int slot = it * 256 + tid;
    int n = slot >> 5, kc = slot & 31;
    gl_lds16(WT + ((mod << 6) + n) * 256 + kc * 8, Bs + slot * 8);
  }

  f4 acc[4][4];
#pragma unroll
  for (int a = 0; a < 4; ++a)
#pragma unroll
    for (int bq = 0; bq < 4; ++bq) acc[a][bq] = f4{0.f, 0.f, 0.f, 0.f};

  for (int kt = 0; kt < 4; ++kt) {
#pragma unroll
    for (int it = 0; it < 8; ++it) {
      int slot = it * 256 + tid;
      int r = slot >> 3, kc = slot & 7;
      long m = m0r + r;
      long g = (m >> shf) * 2048 + ((m & (long)(Ti - 1)) << mod);
      gl_lds16(Xh + g * 256 + kt * 64 + kc * 8, As + slot * 8);
    }
    __syncthreads();
#pragma unroll
    for (int ks = 0; ks < 2; ++ks) {
      h8 af[4], bf[4];
#pragma unroll
      for (int mi = 0; mi < 4; ++mi)
        af[mi] = *(const h8*)&As[(wv * 64 + mi * 16 + lr) * 64 + ks * 32 + lk];
#pragma unroll
      for (int ni = 0; ni < 4; ++ni)
        bf[ni] = *(const h8*)&Bs[(ni * 16 + lr) * 256 + kt * 64 + ks * 32 + lk];
#pragma unroll
      for (int mi = 0; mi < 4; ++mi)
#pragma unroll
        for (int ni = 0; ni < 4; ++ni)
          acc[mi][ni] = __builtin_amdgcn_mfma_f32_16x16x32_f16(af[mi], bf[ni], acc[mi][ni], 0, 0, 0);
    }
    __syncthreads();
  }

  const long xb = 16777216L - (16777216L >> mod);
#pragma unroll
  for (int ni = 0; ni < 4; ++ni) {
    int n = ni * 16 + lr;
    float bv = bias[(mod << 6) + n];
#pragma unroll
    for (int mi = 0; mi < 4; ++mi) {
      f4 cf = acc[mi][ni];
#pragma unroll
      for (int q = 0; q < 4; ++q) {
        long m = m0r + wv * 64 + mi * 16 + (l >> 4) * 4 + q;
        xout[xb + m * 64 + n] = (half_t)(cf[q] + bv);
      }
    }
  }
}

// ---------------- scan round 4 ----------------
// Roles (8 waves):
//   waves 0-3: m0. chunk q0=l>>4 (4 x 128 rows), col c0 = wv*16+(l&15).
//     Weights loaded ROTATED by 2*q0 groups so the per-step wreg index is
//     STATIC; the matching rotation is applied to the LDS h-address only.
//   waves 4-5: m1. chunk q1=l>>5 (2 x 224 rows), col cc=(wv&1)*32+(l&31).
//   waves 6-7: m2 K-split (chunk q1, col cc) PLUS no-split modules:
//     wave 6: m4 (col=l, per 16), m6 (col=l, per 64)
//     wave 7: m3 (col=l, per 8), m5 (per 32), m7 (per 128)
// m3..m7 f16 weights in LDS at [base + p*64 + col] (lane-consecutive reads).

template <int PAIRS>
__device__ __forceinline__ float dotL(const h2* hp, const h2* wp) {
  float a0 = 0.f, a1 = 0.f, a2 = 0.f, a3 = 0.f;
#pragma unroll
  for (int p = 0; p < PAIRS; p += 4) {
    a0 = dot2f(hp[p], wp[(p) * 64], a0);
    a1 = dot2f(hp[p + 1], wp[(p + 1) * 64], a1);
    a2 = dot2f(hp[p + 2], wp[(p + 2) * 64], a2);
    a3 = dot2f(hp[p + 3], wp[(p + 3) * 64], a3);
  }
  return (a0 + a1) + (a2 + a3);
}

__global__ __launch_bounds__(512, 2) void cw_scan4(
    const half_t* __restrict__ xbuf,
    const float* __restrict__ Wc0, const float* __restrict__ Wc1,
    const float* __restrict__ Wc2, const float* __restrict__ Wc3,
    const float* __restrict__ Wc4, const float* __restrict__ Wc5,
    const float* __restrict__ Wc6, const float* __restrict__ Wc7,
    float* __restrict__ out) {
  const int b = blockIdx.x;
  const int tid = threadIdx.x;
  const int wv = tid >> 6;
  const int l = tid & 63;

  __shared__ alignas(16) half_t hbuf[2][512];
  __shared__ h2 wlds[30720];  // m3:0(160p) m4:10240(128p) m5:18432(96p) m6:24576(64p) m7:28672(32p)

  const int q0 = l >> 4;
  const int c0 = (wv << 4) + (l & 15);
  const int q1 = l >> 5;
  const int cc = ((wv & 1) << 5) + (l & 31);  // m1 col (wv4,5) / m2 col (wv6,7)

  h2 wreg[112];
#pragma unroll
  for (int p = 0; p < 112; ++p) wreg[p] = h2{(half_t)0.f, (half_t)0.f};

  float hs0 = 0.f, hsA = 0.f, hsB = 0.f, hsC = 0.f;
  float xr0 = 0.f, xr1 = 0.f, xr2 = 0.f, xr3 = 0.f;
  float xrA = 0.f, xrB = 0.f, xrC = 0.f;

  // ---- register weights ----
  if (wv < 4) {
    // wreg[g*4+j] holds the weight for h-pair position ((g+2*q0)&15)*4+j of
    // chunk q0 -- static destination index, rotation folded into source row.
#pragma unroll
    for (int g = 0; g < 16; ++g) {
      const int gg = (g + 2 * q0) & 15;
#pragma unroll
      for (int j = 0; j < 4; ++j) {
        int r = (q0 << 7) + 2 * (gg * 4 + j);
        wreg[g * 4 + j] = h2{(half_t)Wc0[r * 64 + c0], (half_t)Wc0[(r + 1) * 64 + c0]};
      }
    }
  } else if (wv < 6) {
#pragma unroll
    for (int p = 0; p < 112; ++p) {
      int r = q1 * 224 + 2 * p;
      wreg[p] = h2{(half_t)Wc1[r * 64 + cc], (half_t)Wc1[(r + 1) * 64 + cc]};
    }
  } else {
#pragma unroll
    for (int p = 0; p < 96; ++p) {
      int r = q1 * 192 + 2 * p;
      wreg[p] = h2{(half_t)Wc2[r * 64 + cc], (half_t)Wc2[(r + 1) * 64 + cc]};
    }
  }

  // ---- m3..m7 weights -> LDS (simple [p][col] layout) ----
  for (int e = tid; e < 160 * 64; e += 512) {
    int p = e >> 6, col = e & 63;
    wlds[0 + e] = h2{(half_t)Wc3[(2 * p) * 64 + col], (half_t)Wc3[(2 * p + 1) * 64 + col]};
  }
  for (int e = tid; e < 128 * 64; e += 512) {
    int p = e >> 6, col = e & 63;
    wlds[10240 + e] = h2{(half_t)Wc4[(2 * p) * 64 + col], (half_t)Wc4[(2 * p + 1) * 64 + col]};
  }
  for (int e = tid; e < 96 * 64; e += 512) {
    int p = e >> 6, col = e & 63;
    wlds[18432 + e] = h2{(half_t)Wc5[(2 * p) * 64 + col], (half_t)Wc5[(2 * p + 1) * 64 + col]};
  }
  for (int e = tid; e < 64 * 64; e += 512) {
    int p = e >> 6, col = e & 63;
    wlds[24576 + e] = h2{(half_t)Wc6[(2 * p) * 64 + col], (half_t)Wc6[(2 * p + 1) * 64 + col]};
  }
  for (int e = tid; e < 32 * 64; e += 512) {
    int p = e >> 6, col = e & 63;
    wlds[28672 + e] = h2{(half_t)Wc7[(2 * p) * 64 + col], (half_t)Wc7[(2 * p + 1) * 64 + col]};
  }
  hbuf[0][tid] = (half_t)0.f;
  hbuf[1][tid] = (half_t)0.f;

  // ---- x pointers (compact layout; bases in halves) ----
  const half_t* xp0 = xbuf + ((long)b << 17) + c0;             // m0: b*2048*64
  const half_t* xp1 = xbuf + 8388608L + ((long)b << 16) + cc;  // m1: b*1024*64
  const half_t* xp2 = xbuf + 12582912L + ((long)b << 15) + cc; // m2: b*512*64
  const half_t* xpA = xbuf;
  const half_t* xpB = xbuf;
  const half_t* xpC = xbuf;
  if (wv == 6) {
    xpA = xbuf + 15728640L + ((long)b << 13) + l;  // m4: b*128*64
    xpB = xbuf + 16515072L + ((long)b << 11) + l;  // m6: b*32*64
  } else if (wv == 7) {
    xpA = xbuf + 14680064L + ((long)b << 14) + l;  // m3: b*256*64
    xpB = xbuf + 16252928L + ((long)b << 12) + l;  // m5: b*64*64
    xpC = xbuf + 16646144L + ((long)b << 10) + l;  // m7: b*16*64
  }

  // ---- initial prefetch ----
  if (wv < 4) {
    if (l < 16) {
      xr0 = (float)xp0[0];
      xr1 = (float)xp0[64];
      xr2 = (float)xp0[128];
      xr3 = (float)xp0[192];
    }
  } else if (wv < 6) {
    if (l < 32) {
      xr0 = (float)xp1[0];
      xr1 = (float)xp1[64];
    }
  } else if (wv == 6) {
    if (l < 32) xr0 = (float)xp2[0];
    xrA = (float)xpA[0];
    xrB = (float)xpB[0];
  } else {
    if (l < 32) xr0 = (float)xp2[0];
    xrA = (float)xpA[0];
    xrB = (float)xpB[0];
    xrC = (float)xpC[0];
  }
  __syncthreads();

  auto step = [&](auto offc, int t, const half_t* hin, half_t* hout) {
    constexpr int OFF = decltype(offc)::value;
    const h2* hin2 = (const h2*)hin;
    if (wv < 4) {
      // ---- m0: every step; LDS address rotated, wreg index STATIC ----
      const h2* hp = hin2 + (q0 << 6);
      float a0 = 0.f, a1 = 0.f, a2 = 0.f, a3 = 0.f;
#pragma unroll
      for (int g = 0; g < 16; ++g) {
        const int gg = (g + 2 * q0) & 15;  // runtime: LDS address only
        a0 = dot2f(hp[gg * 4 + 0], wreg[g * 4 + 0], a0);
        a1 = dot2f(hp[gg * 4 + 1], wreg[g * 4 + 1], a1);
        a2 = dot2f(hp[gg * 4 + 2], wreg[g * 4 + 2], a2);
        a3 = dot2f(hp[gg * 4 + 3], wreg[g * 4 + 3], a3);
      }
      float v = (a0 + a1) + (a2 + a3);
      v += __shfl_xor(v, 16);
      v += __shfl_xor(v, 32);
      if (l < 16) {
        float xv;
        if constexpr (OFF == 0) xv = xr0;
        else if constexpr (OFF == 1) xv = xr1;
        else if constexpr (OFF == 2) xv = xr2;
        else xv = xr3;
        hs0 = fast_tanh(v + xv);
        hout[c0] = (half_t)hs0;
        int tn = t + OFF + 4;
        if (tn < 2048) {
          float nv = (float)xp0[(long)tn << 6];
          if constexpr (OFF == 0) xr0 = nv;
          else if constexpr (OFF == 1) xr1 = nv;
          else if constexpr (OFF == 2) xr2 = nv;
          else xr3 = nv;
        }
      }
    } else if (wv < 6) {
      // ---- m1: update on even t ----
      if constexpr ((OFF & 1) == 0) {
        const h2* hp = hin2 + 32 + 112 * q1;
        float a0 = 0.f, a1 = 0.f, a2 = 0.f, a3 = 0.f;
#pragma unroll
        for (int p = 0; p < 112; p += 4) {
          a0 = dot2f(hp[p], wreg[p], a0);
          a1 = dot2f(hp[p + 1], wreg[p + 1], a1);
          a2 = dot2f(hp[p + 2], wreg[p + 2], a2);
          a3 = dot2f(hp[p + 3], wreg[p + 3], a3);
        }
        float v = (a0 + a1) + (a2 + a3);
        v += __shfl_xor(v, 32);
        if (l < 32) {
          float xv = (OFF == 0) ? xr0 : xr1;
          hs0 = fast_tanh(v + xv);
          hout[64 + cc] = (half_t)hs0;
          int tn = t + OFF + 4;
          if (tn < 2048) {
            float nv = (float)xp1[(long)(tn >> 1) << 6];
            if constexpr (OFF == 0) xr0 = nv;
            else xr1 = nv;
          }
        }
      } else {
        if (l < 32) {
          hs0 = fast_tanh(hs0);
          hout[64 + cc] = (half_t)hs0;
        }
      }
    } else if (wv == 6) {
      // ---- m2-half + m4 + m6 ----
      float v2 = 0.f, dA = 0.f, dB = 0.f;
      bool uA = false, uB = false;
      if constexpr (OFF == 0) {
        const h2* hp = hin2 + 64 + 96 * q1;
        float a0 = 0.f, a1 = 0.f, a2 = 0.f, a3 = 0.f;
#pragma unroll
        for (int p = 0; p < 96; p += 4) {
          a0 = dot2f(hp[p], wreg[p], a0);
          a1 = dot2f(hp[p + 1], wreg[p + 1], a1);
          a2 = dot2f(hp[p + 2], wreg[p + 2], a2);
          a3 = dot2f(hp[p + 3], wreg[p + 3], a3);
        }
        v2 = (a0 + a1) + (a2 + a3);
        v2 += __shfl_xor(v2, 32);
        uA = (t & 15) == 0;
        uB = (t & 63) == 0;
        if (uA) dA = dotL<128>(hin2 + 128, wlds + 10240 + l);
        if (uB) dB = dotL<64>(hin2 + 192, wlds + 24576 + l);
      }
      if (l < 32) {
        if constexpr (OFF == 0) {
          hs0 = fast_tanh(v2 + xr0);
          int ni = (t >> 2) + 1;
          if (ni < 512) xr0 = (float)xp2[(long)ni << 6];
        } else {
          hs0 = fast_tanh(hs0);
        }
        hout[128 + cc] = (half_t)hs0;
      }
      if (OFF == 0 && uA) {
        hsA = fast_tanh(dA + xrA);
        int ni = (t >> 4) + 1;
        if (ni < 128) xrA = (float)xpA[(long)ni << 6];
      } else {
        hsA = fast_tanh(hsA);
      }
      hout[256 + l] = (half_t)hsA;
      if (OFF == 0 && uB) {
        hsB = fast_tanh(dB + xrB);
        int ni = (t >> 6) + 1;
        if (ni < 32) xrB = (float)xpB[(long)ni << 6];
      } else {
        hsB = fast_tanh(hsB);
      }
      hout[384 + l] = (half_t)hsB;
    } else {
      // ---- m2-half + m3 + m5 + m7 ----
      float v2 = 0.f, dA = 0.f, dB = 0.f, dC = 0.f;
      bool uA = false, uB = false, uC = false;
      if constexpr (OFF == 0) {
        const h2* hp = hin2 + 64 + 96 * q1;
        float a0 = 0.f, a1 = 0.f, a2 = 0.f, a3 = 0.f;
#pragma unroll
        for (int p = 0; p < 96; p += 4) {
          a0 = dot2f(hp[p], wreg[p], a0);
          a1 = dot2f(hp[p + 1], wreg[p + 1], a1);
          a2 = dot2f(hp[p + 2], wreg[p + 2], a2);
          a3 = dot2f(hp[p + 3], wreg[p + 3], a3);
        }
        v2 = (a0 + a1) + (a2 + a3);
        v2 += __shfl_xor(v2, 32);
        uA = (t & 7) == 0;
        uB = (t & 31) == 0;
        uC = (t & 127) == 0;
        if (uA) dA = dotL<160>(hin2 + 96, wlds + 0 + l);
        if (uB) dB = dotL<96>(hin2 + 160, wlds + 18432 + l);
        if (uC) dC = dotL<32>(hin2 + 224, wlds + 28672 + l);
      }
      if (l < 32) {
        if constexpr (OFF == 0) {
          hs0 = fast_tanh(v2 + xr0);
          int ni = (t >> 2) + 1;
          if (ni < 512) xr0 = (float)xp2[(long)ni << 6];
        } else {
          hs0 = fast_tanh(hs0);
        }
        hout[128 + cc] = (half_t)hs0;
      }
      if (OFF == 0 && uA) {
        hsA = fast_tanh(dA + xrA);
        int ni = (t >> 3) + 1;
        if (ni < 256) xrA = (float)xpA[(long)ni << 6];
      } else {
        hsA = fast_tanh(hsA);
      }
      hout[192 + l] = (half_t)hsA;
      if (OFF == 0 && uB) {
        hsB = fast_tanh(dB + xrB);
        int ni = (t >> 5) + 1;
        if (ni < 64) xrB = (float)xpB[(long)ni << 6];
      } else {
        hsB = fast_tanh(hsB);
      }
      hout[320 + l] = (half_t)hsB;
      if (OFF == 0 && uC) {
        hsC = fast_tanh(dC + xrC);
        int ni = (t >> 7) + 1;
        if (ni < 16) xrC = (float)xpC[(long)ni << 6];
      } else {
        hsC = fast_tanh(hsC);
      }
      hout[448 + l] = (half_t)hsC;
    }
    __syncthreads();
  };

  for (int t = 0; t < 2048; t += 4) {
    step(std::integral_constant<int, 0>{}, t, hbuf[0], hbuf[1]);
    step(std::integral_constant<int, 1>{}, t, hbuf[1], hbuf[0]);
    step(std::integral_constant<int, 2>{}, t, hbuf[0], hbuf[1]);
    step(std::integral_constant<int, 3>{}, t, hbuf[1], hbuf[0]);
  }

  // ---- output ----
  float* ob = out + ((long)b << 9);
  if (wv < 4) {
    if (l < 16) ob[c0] = hs0;
  } else if (wv < 6) {
    if (l < 32) ob[64 + cc] = hs0;
  } else if (wv == 6) {
    if (l < 32) ob[128 + cc] = hs0;
    ob[256 + l] = hsA;
    ob[384 + l] = hsB;
  } else {
    if (l < 32) ob[128 + cc] = hs0;
    ob[192 + l] = hsA;
    ob[320 + l] = hsB;
    ob[448 + l] = hsC;
  }
}

// ---------------- launcher ----------------
extern "C" void kernel_launch(void* const* d_in, const int* in_sizes, int n_in,
                              void* d_out, int out_size, void* d_ws, size_t ws_size,
                              hipStream_t stream) {
  const float* X = (const float*)d_in[0];
  const float* W = (const float*)d_in[1];
  const float* bias = (const float*)d_in[2];
  const float* Wc0 = (const float*)d_in[3];
  const float* Wc1 = (const float*)d_in[4];
  const float* Wc2 = (const float*)d_in[5];
  const float* Wc3 = (const float*)d_in[6];
  const float* Wc4 = (const float*)d_in[7];
  const float* Wc5 = (const float*)d_in[8];
  const float* Wc6 = (const float*)d_in[9];
  const float* Wc7 = (const float*)d_in[10];
  float* out = (float*)d_out;

  half_t* Xh = (half_t*)d_ws;                       // 67,108,864 B
  half_t* WT = (half_t*)((char*)d_ws + 67108864);   //    262,144 B
  half_t* xbuf = (half_t*)((char*)d_ws + 67371008); // 33,423,360 B

  cw_cvt_x<<<4096, 256, 0, stream>>>(X, Xh, 8388608L);
  cw_cvt_wt<<<512, 256, 0, stream>>>(W, WT);
  dim3 g(512, 8);
  cw_xproj<<<g, 256, 0, stream>>>(Xh, WT, bias, xbuf);
  cw_scan4<<<64, 512, 0, stream>>>(xbuf, Wc0, Wc1, Wc2, Wc3, Wc4, Wc5, Wc6, Wc7, out);
}